// Round 2
// baseline (124.438 us; speedup 1.0000x reference)
//
#include <hip/hip_runtime.h>
#include <hip/hip_bf16.h>
#include <stdint.h>

// C = (B,16,16): diag (k,k) = sigmoid(x·Wd[k]+bd[k]); off (i,j) = -softplus(x·Wo[r]+bo[r])
// Permuted GEMM: out[b][c], c=i*16+j. M=65536 N=256 K=1024, bf16 MFMA 16x16x32.
// R2: W read direct from L2 in fragment order (no LDS staging); LDS = A dbuf only
// (32 KB); 1024 threads / 16 waves (4Mx4N) -> 16 waves/CU.

typedef __bf16 bf16x8 __attribute__((ext_vector_type(8)));
typedef float f32x4 __attribute__((ext_vector_type(4)));

#define THREADS 1024
#define BM 128
#define KSTEPS 16        // 1024 / 64
#define WTILE 32768      // one K-step image: 2(ks) x 4(l4) x 256 cols x 16B
#define WBYTES (WTILE * KSTEPS)

__device__ __forceinline__ unsigned bf_rtne(unsigned u) {
  return (u + 0x7fffu + ((u >> 16) & 1u)) >> 16;
}
__device__ __forceinline__ unsigned pack2(float lo, float hi) {
  return bf_rtne(__float_as_uint(lo)) | (bf_rtne(__float_as_uint(hi)) << 16);
}

// Weight image in MFMA-fragment order:
// element (c, k):  t=k>>6, ks=(k>>5)&1, q=(k>>3)&3, e=k&7
// byte addr = t*WTILE + ks*16384 + q*4096 + c*16 + e*2
// => a wave's B-fragment load (lane=q*16+l15 reads col c=wn*64+n*16+l15) is
//    four 256B-contiguous segments. Perfectly coalesced, L2-resident (512 KB).
__global__ void prep_kernel(const float* __restrict__ Wd, const float* __restrict__ bd,
                            const float* __restrict__ Wo, const float* __restrict__ bo,
                            char* __restrict__ wbuf, float* __restrict__ bias) {
  const int c = blockIdx.x;    // 0..255 output col
  const int t = threadIdx.x;   // 0..255, 4 consecutive k each
  const int i = c >> 4, j = c & 15;
  const float* src;
  float b;
  if (i == j) { src = Wd + i * 1024; b = bd[i]; }
  else { int r = i * 15 + (j < i ? j : j - 1); src = Wo + r * 1024; b = bo[r]; }
  if (t == 0) bias[c] = b;
  const int kk = t * 4;
  const int ts = kk >> 6, ks = (kk >> 5) & 1, q = (kk >> 3) & 3, e = kk & 7;
  float4 v = *reinterpret_cast<const float4*>(src + kk);
  uint2 h;
  h.x = pack2(v.x, v.y);
  h.y = pack2(v.z, v.w);
  *reinterpret_cast<uint2*>(wbuf + ts * WTILE + ks * 16384 + q * 4096 + c * 16 + e * 2) = h;
}

__global__ __launch_bounds__(THREADS, 4) void cap_main(
    const float* __restrict__ x, const char* __restrict__ wbuf,
    const float* __restrict__ bias, float* __restrict__ out) {
  __shared__ char smem[32768];  // A dbuf: 2 x (128 rows x 64 k x 2B = 16 KB)

  const int tid = threadIdx.x;
  const int wid = tid >> 6;
  const int lane = tid & 63;
  const int l15 = lane & 15;
  const int l4 = lane >> 4;
  const int wm = wid >> 2;  // 0..3  (32 rows each)
  const int wn = wid & 3;   // 0..3  (64 cols each)

  const size_t blkRow = (size_t)blockIdx.x * BM;

  // A staging: each thread owns 8 consecutive floats of the 128x64 slice
  const int ar = tid >> 3;            // row 0..127
  const int ac = (tid & 7) * 8;       // col 0..56
  const float* xs = x + (blkRow + (size_t)ar) * 1024 + ac;
  const unsigned aw = (unsigned)((ar * 128 + ac * 2) ^ ((ar & 7) << 4));

  // A fragment base: row = wm*32 + m*16 + l15, k-bytes = ks*64 + l4*16
  const unsigned abase = (unsigned)((wm * 32 + l15) * 128 + l4 * 16);
  const unsigned sxor = (unsigned)((l15 & 7) << 4);

  // B fragment base (per-lane, invariant part)
  const char* wb = wbuf + l4 * 4096 + (wn * 64 + l15) * 16;

  f32x4 acc[2][4];
#pragma unroll
  for (int m = 0; m < 2; ++m)
#pragma unroll
    for (int n = 0; n < 4; ++n) acc[m][n] = (f32x4){0.f, 0.f, 0.f, 0.f};

  // ---- prologue: stage A tile 0 ----
  {
    float4 p0 = *reinterpret_cast<const float4*>(xs);
    float4 p1 = *reinterpret_cast<const float4*>(xs + 4);
    uint4 w;
    w.x = pack2(p0.x, p0.y); w.y = pack2(p0.z, p0.w);
    w.z = pack2(p1.x, p1.y); w.w = pack2(p1.z, p1.w);
    *reinterpret_cast<uint4*>(smem + aw) = w;
  }
  __syncthreads();

  for (int t = 0; t < KSTEPS; ++t) {
    const int cur = t & 1;
    const char* Ac = smem + cur * 16384;
    char* An = smem + (cur ^ 1) * 16384;

    // issue next A tile's global loads early (T14: hide HBM under MFMA)
    float4 p0, p1;
    if (t + 1 < KSTEPS) {
      p0 = *reinterpret_cast<const float4*>(xs + (t + 1) * 64);
      p1 = *reinterpret_cast<const float4*>(xs + (t + 1) * 64 + 4);
    }

    // B fragments direct from L2 (coalesced 4x256B per load inst)
    const char* wt = wb + t * WTILE;
    bf16x8 bfr[2][4];
#pragma unroll
    for (int ks = 0; ks < 2; ++ks)
#pragma unroll
      for (int n = 0; n < 4; ++n)
        bfr[ks][n] = *reinterpret_cast<const bf16x8*>(wt + ks * 16384 + n * 256);

    // A fragments from LDS
    bf16x8 af[2][2];
#pragma unroll
    for (int ks = 0; ks < 2; ++ks)
#pragma unroll
      for (int m = 0; m < 2; ++m)
        af[ks][m] = *reinterpret_cast<const bf16x8*>(Ac + ((abase + m * 2048 + ks * 64) ^ sxor));

#pragma unroll
    for (int ks = 0; ks < 2; ++ks)
#pragma unroll
      for (int m = 0; m < 2; ++m)
#pragma unroll
        for (int n = 0; n < 4; ++n)
          acc[m][n] = __builtin_amdgcn_mfma_f32_16x16x32_bf16(af[ks][m], bfr[ks][n], acc[m][n], 0, 0, 0);

    if (t + 1 < KSTEPS) {
      uint4 w;
      w.x = pack2(p0.x, p0.y); w.y = pack2(p0.z, p0.w);
      w.z = pack2(p1.x, p1.y); w.w = pack2(p1.z, p1.w);
      *reinterpret_cast<uint4*>(An + aw) = w;
    }
    __syncthreads();
  }

  // ---- epilogue: bias + activation + store ----
#pragma unroll
  for (int n = 0; n < 4; ++n) {
    const int col = wn * 64 + n * 16 + l15;
    const float bs = bias[col];
    const bool diag = (col % 17) == 0;
#pragma unroll
    for (int m = 0; m < 2; ++m) {
      const size_t row0 = blkRow + (size_t)(wm * 32 + m * 16 + l4 * 4);
#pragma unroll
      for (int j2 = 0; j2 < 4; ++j2) {
        float v = acc[m][n][j2] + bs;
        float e = __expf(-fabsf(v));
        float sig = (v >= 0.f) ? 1.f / (1.f + e) : e / (1.f + e);
        float sp = fmaxf(v, 0.f) + __logf(1.f + e);
        out[(row0 + j2) * 256 + col] = diag ? sig : -sp;
      }
    }
  }
}

extern "C" void kernel_launch(void* const* d_in, const int* in_sizes, int n_in,
                              void* d_out, int out_size, void* d_ws, size_t ws_size,
                              hipStream_t stream) {
  const float* x = (const float*)d_in[0];
  const float* Wd = (const float*)d_in[1];
  const float* bd = (const float*)d_in[2];
  const float* Wo = (const float*)d_in[3];
  const float* bo = (const float*)d_in[4];
  float* out = (float*)d_out;
  char* wbuf = (char*)d_ws;                  // 512 KiB weight image
  float* bias = (float*)(wbuf + WBYTES);     // 1 KiB bias

  prep_kernel<<<dim3(256), dim3(256), 0, stream>>>(Wd, bd, Wo, bo, wbuf, bias);
  cap_main<<<dim3(512), dim3(THREADS), 0, stream>>>(x, wbuf, bias, out);
}

// Round 3
// 107.888 us; speedup vs baseline: 1.1534x; 1.1534x over previous
//
#include <hip/hip_runtime.h>
#include <hip/hip_bf16.h>
#include <stdint.h>

// C = (B,16,16): diag (k,k)=sigmoid(x·Wd[k]+bd[k]); off (i,j)=-softplus(x·Wo[r]+bo[r])
// Permuted GEMM out[b][c], c=i*16+j. M=65536 N=256 K=1024, bf16 MFMA 16x16x32.
// R3: memory-paced design. BM=256,BN=256,BK=64, 256 blocks (1/CU), 8 waves.
// MFMA reads ONLY LDS (A+B staged one step ahead) -> no vmem wait before MFMA.
// B via global_load_lds from pre-swizzled L2-resident image (loaded once per
// block per step: 134 MB total L2 traffic vs R2's 1.05 TB).

typedef __bf16 bf16x8 __attribute__((ext_vector_type(8)));
typedef float f32x4 __attribute__((ext_vector_type(4)));

#define THREADS 512
#define BM 256
#define KSTEPS 16
#define WTILE 32768               // per-K-step W image: 256 cols x 64 k x 2B
#define WBYTES (WTILE * KSTEPS)   // 512 KiB

__device__ __forceinline__ unsigned bf_rtne(unsigned u) {
  return (u + 0x7fffu + ((u >> 16) & 1u)) >> 16;
}
__device__ __forceinline__ unsigned pack2(float lo, float hi) {
  return bf_rtne(__float_as_uint(lo)) | (bf_rtne(__float_as_uint(hi)) << 16);
}

__device__ __forceinline__ void gload_lds16(const void* g, void* l) {
  __builtin_amdgcn_global_load_lds(
      (const __attribute__((address_space(1))) unsigned int*)g,
      (__attribute__((address_space(3))) unsigned int*)l, 16, 0, 0);
}

// W image per K-step: byte(c,k) = (c*128 + k*2) ^ ((c&7)<<4). gload_lds copies
// it linearly -> LDS holds the swizzled layout; reads apply the same XOR.
__global__ void prep_kernel(const float* __restrict__ Wd, const float* __restrict__ bd,
                            const float* __restrict__ Wo, const float* __restrict__ bo,
                            char* __restrict__ wbuf, float* __restrict__ bias) {
  const int c = blockIdx.x;    // 0..255 output col
  const int t = threadIdx.x;   // 0..255, 4 consecutive k each
  const int i = c >> 4, j = c & 15;
  const float* src;
  float b;
  if (i == j) { src = Wd + i * 1024; b = bd[i]; }
  else { int r = i * 15 + (j < i ? j : j - 1); src = Wo + r * 1024; b = bo[r]; }
  if (t == 0) bias[c] = b;
  const int kk = t * 4;
  const int kstep = kk >> 6, k6 = kk & 63;
  float4 v = *reinterpret_cast<const float4*>(src + kk);
  uint2 h;
  h.x = pack2(v.x, v.y);
  h.y = pack2(v.z, v.w);
  const unsigned off = (unsigned)((c * 128 + k6 * 2) ^ ((c & 7) << 4));
  *reinterpret_cast<uint2*>(wbuf + kstep * WTILE + off) = h;
}

__global__ __launch_bounds__(THREADS, 2) void cap_main(
    const float* __restrict__ x, const char* __restrict__ wbuf,
    const float* __restrict__ bias, float* __restrict__ out) {
  __shared__ char smem[131072];  // A[2]: 2x32K @0, B[2]: 2x32K @65536

  const int tid = threadIdx.x;
  const int wid = tid >> 6;
  const int lane = tid & 63;
  const int l15 = lane & 15;
  const int l4 = lane >> 4;
  const int wm = wid >> 2;  // 0..1 -> 128 rows each
  const int wn = wid & 3;   // 0..3 -> 64 cols each

  const size_t blkRow = (size_t)blockIdx.x * BM;

  // ---- A staging map: inst q (0..7) reads 1 KB/wave contiguous ----
  // thread covers row r = q*32 + (tid>>4), k-quad (tid&15)*4 within the step slice
  const int fr = tid >> 4;   // 0..31
  const int fc = tid & 15;   // 0..15
  const float* xs = x + (blkRow + (size_t)fr) * 1024 + fc * 4;  // + t*64 + q*32*1024
  const unsigned aw0 = (unsigned)((fr * 128 + fc * 8) ^ ((fr & 7) << 4));  // + q*4096

  // ---- fragment read bases ----
  const unsigned abase = (unsigned)((wm * 128 + l15) * 128 + l4 * 16);  // + m*2048 + ks*64
  const unsigned bbase = (unsigned)((wn * 64 + l15) * 128 + l4 * 16);   // + n*2048 + ks*64
  const unsigned sxor = (unsigned)((l15 & 7) << 4);

  f32x4 acc[8][4];
#pragma unroll
  for (int m = 0; m < 8; ++m)
#pragma unroll
    for (int n = 0; n < 4; ++n) acc[m][n] = (f32x4){0.f, 0.f, 0.f, 0.f};

  // ---- prologue: stage tile 0 ----
  {
    float4 xq[8];
#pragma unroll
    for (int q = 0; q < 8; ++q)
      xq[q] = *reinterpret_cast<const float4*>(xs + q * 32 * 1024);
#pragma unroll
    for (int r = 0; r < 4; ++r)
      gload_lds16(wbuf + r * 8192 + tid * 16, smem + 65536 + r * 8192 + wid * 1024);
#pragma unroll
    for (int q = 0; q < 8; ++q) {
      uint2 h;
      h.x = pack2(xq[q].x, xq[q].y);
      h.y = pack2(xq[q].z, xq[q].w);
      *reinterpret_cast<uint2*>(smem + aw0 + q * 4096) = h;
    }
  }
  __syncthreads();

  for (int t = 0; t < KSTEPS; ++t) {
    const int cur = t & 1;
    const char* Ac = smem + cur * 32768;
    const char* Bc = smem + 65536 + cur * 32768;
    char* An = smem + (cur ^ 1) * 32768;
    char* Bn = smem + 65536 + (cur ^ 1) * 32768;

    // issue next-step loads FIRST (x oldest -> pack waits vmcnt(4), keeping
    // B gloads in flight; barrier's vmcnt(0) lands after full MFMA-phase cover)
    float4 xq[8];
    if (t + 1 < KSTEPS) {
      const float* xsp = xs + (t + 1) * 64;
#pragma unroll
      for (int q = 0; q < 8; ++q)
        xq[q] = *reinterpret_cast<const float4*>(xsp + q * 32 * 1024);
      const char* wsp = wbuf + (t + 1) * WTILE;
#pragma unroll
      for (int r = 0; r < 4; ++r)
        gload_lds16(wsp + r * 8192 + tid * 16, Bn + r * 8192 + wid * 1024);
    }

    // MFMA phase: LDS only, no vmem dependency
#pragma unroll
    for (int ks = 0; ks < 2; ++ks) {
      bf16x8 bfr[4], af[8];
#pragma unroll
      for (int n = 0; n < 4; ++n)
        bfr[n] = *reinterpret_cast<const bf16x8*>(Bc + ((bbase + n * 2048 + ks * 64) ^ sxor));
#pragma unroll
      for (int m = 0; m < 8; ++m)
        af[m] = *reinterpret_cast<const bf16x8*>(Ac + ((abase + m * 2048 + ks * 64) ^ sxor));
#pragma unroll
      for (int m = 0; m < 8; ++m)
#pragma unroll
        for (int n = 0; n < 4; ++n)
          acc[m][n] = __builtin_amdgcn_mfma_f32_16x16x32_bf16(af[m], bfr[n], acc[m][n], 0, 0, 0);
    }

    // late: pack + ds_write next A tile (waits only on the x loads)
    if (t + 1 < KSTEPS) {
#pragma unroll
      for (int q = 0; q < 8; ++q) {
        uint2 h;
        h.x = pack2(xq[q].x, xq[q].y);
        h.y = pack2(xq[q].z, xq[q].w);
        *reinterpret_cast<uint2*>(An + aw0 + q * 4096) = h;
      }
    }
    __syncthreads();
  }

  // ---- epilogue: bias + activation + store ----
#pragma unroll
  for (int n = 0; n < 4; ++n) {
    const int col = wn * 64 + n * 16 + l15;
    const float bs = bias[col];
    const bool diag = (col % 17) == 0;
#pragma unroll
    for (int m = 0; m < 8; ++m) {
      const size_t row0 = blkRow + (size_t)(wm * 128 + m * 16 + l4 * 4);
#pragma unroll
      for (int j2 = 0; j2 < 4; ++j2) {
        float v = acc[m][n][j2] + bs;
        float e = __expf(-fabsf(v));
        float sig = (v >= 0.f) ? 1.f / (1.f + e) : e / (1.f + e);
        float sp = fmaxf(v, 0.f) + __logf(1.f + e);
        out[(row0 + j2) * 256 + col] = diag ? sig : -sp;
      }
    }
  }
}

extern "C" void kernel_launch(void* const* d_in, const int* in_sizes, int n_in,
                              void* d_out, int out_size, void* d_ws, size_t ws_size,
                              hipStream_t stream) {
  const float* x = (const float*)d_in[0];
  const float* Wd = (const float*)d_in[1];
  const float* bd = (const float*)d_in[2];
  const float* Wo = (const float*)d_in[3];
  const float* bo = (const float*)d_in[4];
  float* out = (float*)d_out;
  char* wbuf = (char*)d_ws;                  // 512 KiB weight image
  float* bias = (float*)(wbuf + WBYTES);     // 1 KiB bias

  prep_kernel<<<dim3(256), dim3(256), 0, stream>>>(Wd, bd, Wo, bo, wbuf, bias);
  cap_main<<<dim3(256), dim3(THREADS), 0, stream>>>(x, wbuf, bias, out);
}

// Round 4
// 106.726 us; speedup vs baseline: 1.1660x; 1.0109x over previous
//
#include <hip/hip_runtime.h>
#include <hip/hip_bf16.h>
#include <stdint.h>

// C = (B,16,16): diag (k,k)=sigmoid(x·Wd[k]+bd[k]); off (i,j)=-softplus(x·Wo[r]+bo[r])
// Permuted GEMM out[b][c], c=i*16+j. M=65536 N=256 K=1024, bf16 MFMA 16x16x32.
// R4: TLP-first. BM=64, BK=32, 256 thr (4 waves, 1Mx4N), LDS 40KB -> 4 blocks/CU.
// 1024 blocks. B from pre-swizzled L2 image via global_load_lds (dbuf); A reg-staged
// fp32->bf16 (dbuf). Epilogue: LDS transpose -> full-row contiguous f32 stores.

typedef __bf16 bf16x8 __attribute__((ext_vector_type(8)));
typedef float f32x4 __attribute__((ext_vector_type(4)));

#define THREADS 256
#define BM 64
#define KSTEPS 32
#define WIMG 16384                 // per-K-step B image: 256 cols x 32 k x 2B
#define WBYTES (WIMG * KSTEPS)     // 512 KiB

__device__ __forceinline__ unsigned bf_rtne(unsigned u) {
  return (u + 0x7fffu + ((u >> 16) & 1u)) >> 16;
}
__device__ __forceinline__ unsigned pack2(float lo, float hi) {
  return bf_rtne(__float_as_uint(lo)) | (bf_rtne(__float_as_uint(hi)) << 16);
}

__device__ __forceinline__ void gload_lds16(const void* g, void* l) {
  __builtin_amdgcn_global_load_lds(
      (const __attribute__((address_space(1))) unsigned int*)g,
      (__attribute__((address_space(3))) unsigned int*)l, 16, 0, 0);
}

// B image per K-step: byte(c,k) = (c*64 + k*2) ^ (((c>>1)&3)<<4)
// (row stride 64B; XOR places even/odd rows' 16B chunks 2-way per bank slot = free)
__global__ void prep_kernel(const float* __restrict__ Wd, const float* __restrict__ bd,
                            const float* __restrict__ Wo, const float* __restrict__ bo,
                            char* __restrict__ wbuf, float* __restrict__ bias) {
  const int c = blockIdx.x;    // 0..255 output col
  const int t = threadIdx.x;   // 0..255, 4 consecutive k each
  const int i = c >> 4, j = c & 15;
  const float* src;
  float b;
  if (i == j) { src = Wd + i * 1024; b = bd[i]; }
  else { int r = i * 15 + (j < i ? j : j - 1); src = Wo + r * 1024; b = bo[r]; }
  if (t == 0) bias[c] = b;
  const int kk = t * 4;
  const int img = kk >> 5, k5 = kk & 31;
  float4 v = *reinterpret_cast<const float4*>(src + kk);
  uint2 h;
  h.x = pack2(v.x, v.y);
  h.y = pack2(v.z, v.w);
  const unsigned off = (unsigned)((c * 64 + k5 * 2) ^ (((c >> 1) & 3) << 4));
  *reinterpret_cast<uint2*>(wbuf + img * WIMG + off) = h;
}

__global__ __launch_bounds__(THREADS, 4) void cap_main(
    const float* __restrict__ x, const char* __restrict__ wbuf,
    const float* __restrict__ bias, float* __restrict__ out) {
  __shared__ char smem[40960];  // A[2]: 2x4K @0, B[2]: 2x16K @8192; epilogue reuses

  const int tid = threadIdx.x;
  const int wid = tid >> 6;      // wave = wn (0..3), cols wn*64..+63
  const int lane = tid & 63;
  const int l15 = lane & 15;
  const int l4 = lane >> 4;

  const size_t blkRow = (size_t)blockIdx.x * BM;

  // ---- A staging: thread owns 8 consecutive floats of the 64x32 slice ----
  const int ar = tid >> 2;             // row 0..63
  const int akc = tid & 3;             // 16B chunk 0..3
  const float* xs = x + (blkRow + (size_t)ar) * 1024 + akc * 8;
  const unsigned awz = (unsigned)((ar * 64 + akc * 16) ^ (((ar >> 1) & 3) << 4));

  // ---- fragment bases (swizzle term: row>>1&3 == l15>>1&3 since m*16,n*16,wn*64
  //      all contribute multiples of 4 to row>>1) ----
  const unsigned sw = (unsigned)(((l15 >> 1) & 3) << 4);
  const unsigned abase = (unsigned)((l15 * 64 + l4 * 16) ^ sw);               // + m*1024
  const unsigned bbase = (unsigned)(((wid * 64 + l15) * 64 + l4 * 16) ^ sw);  // + n*1024

  f32x4 acc[4][4];
#pragma unroll
  for (int m = 0; m < 4; ++m)
#pragma unroll
    for (int n = 0; n < 4; ++n) acc[m][n] = (f32x4){0.f, 0.f, 0.f, 0.f};

  // ---- prologue: stage step 0 ----
  {
    float4 p0 = *reinterpret_cast<const float4*>(xs);
    float4 p1 = *reinterpret_cast<const float4*>(xs + 4);
#pragma unroll
    for (int i = 0; i < 4; ++i)
      gload_lds16(wbuf + (wid * 4 + i) * 1024 + lane * 16,
                  smem + 8192 + (wid * 4 + i) * 1024);
    uint4 w;
    w.x = pack2(p0.x, p0.y); w.y = pack2(p0.z, p0.w);
    w.z = pack2(p1.x, p1.y); w.w = pack2(p1.z, p1.w);
    *reinterpret_cast<uint4*>(smem + awz) = w;
  }
  __syncthreads();

  for (int t = 0; t < KSTEPS; ++t) {
    const int cur = t & 1;
    const char* Ac = smem + cur * 4096;
    const char* Bc = smem + 8192 + cur * 16384;
    char* An = smem + (cur ^ 1) * 4096;
    char* Bn = smem + 8192 + (cur ^ 1) * 16384;

    // issue next-step loads first: x (oldest -> pack waits vmcnt(4)), then B gloads
    float4 p0, p1;
    if (t + 1 < KSTEPS) {
      const float* xsp = xs + (t + 1) * 32;
      p0 = *reinterpret_cast<const float4*>(xsp);
      p1 = *reinterpret_cast<const float4*>(xsp + 4);
      const char* wsp = wbuf + (t + 1) * WIMG;
#pragma unroll
      for (int i = 0; i < 4; ++i)
        gload_lds16(wsp + (wid * 4 + i) * 1024 + lane * 16, Bn + (wid * 4 + i) * 1024);
    }

    // MFMA phase: LDS-only
    bf16x8 af[4], bfr[4];
#pragma unroll
    for (int m = 0; m < 4; ++m)
      af[m] = *reinterpret_cast<const bf16x8*>(Ac + abase + m * 1024);
#pragma unroll
    for (int n = 0; n < 4; ++n)
      bfr[n] = *reinterpret_cast<const bf16x8*>(Bc + bbase + n * 1024);
#pragma unroll
    for (int m = 0; m < 4; ++m)
#pragma unroll
      for (int n = 0; n < 4; ++n)
        acc[m][n] = __builtin_amdgcn_mfma_f32_16x16x32_bf16(af[m], bfr[n], acc[m][n], 0, 0, 0);

    // late: pack + ds_write next A slice (waits only on x loads, B stays in flight)
    if (t + 1 < KSTEPS) {
      uint4 w;
      w.x = pack2(p0.x, p0.y); w.y = pack2(p0.z, p0.w);
      w.z = pack2(p1.x, p1.y); w.w = pack2(p1.z, p1.w);
      *reinterpret_cast<uint4*>(An + awz) = w;
    }
    __syncthreads();
  }

  // ---- epilogue: activation -> LDS transpose (1040B-padded rows) -> row stores ----
  float bs[4];
#pragma unroll
  for (int n = 0; n < 4; ++n) bs[n] = bias[wid * 64 + n * 16 + l15];

  const int rr2 = tid >> 4;            // 0..15: read-back row
  const int co = (tid & 15) * 16;      // read-back col (floats)
  const char* rdp = smem + rr2 * 1040 + co * 4;

#pragma unroll
  for (int p = 0; p < 4; ++p) {
#pragma unroll
    for (int n = 0; n < 4; ++n) {
      const int col = wid * 64 + n * 16 + l15;
      const bool diag = (col % 17) == 0;
#pragma unroll
      for (int j2 = 0; j2 < 4; ++j2) {
        const int rr = l4 * 4 + j2;
        float v = acc[p][n][j2] + bs[n];
        float e = __expf(-fabsf(v));
        float sig = (v >= 0.f) ? 1.f / (1.f + e) : e / (1.f + e);
        float sp = fmaxf(v, 0.f) + __logf(1.f + e);
        *reinterpret_cast<float*>(smem + rr * 1040 + col * 4) = diag ? sig : -sp;
      }
    }
    __syncthreads();
    float4 o0 = *reinterpret_cast<const float4*>(rdp);
    float4 o1 = *reinterpret_cast<const float4*>(rdp + 16);
    float4 o2 = *reinterpret_cast<const float4*>(rdp + 32);
    float4 o3 = *reinterpret_cast<const float4*>(rdp + 48);
    float* orow = out + (blkRow + (size_t)(p * 16 + rr2)) * 256 + co;
    *reinterpret_cast<float4*>(orow) = o0;
    *reinterpret_cast<float4*>(orow + 4) = o1;
    *reinterpret_cast<float4*>(orow + 8) = o2;
    *reinterpret_cast<float4*>(orow + 12) = o3;
    __syncthreads();
  }
}

extern "C" void kernel_launch(void* const* d_in, const int* in_sizes, int n_in,
                              void* d_out, int out_size, void* d_ws, size_t ws_size,
                              hipStream_t stream) {
  const float* x = (const float*)d_in[0];
  const float* Wd = (const float*)d_in[1];
  const float* bd = (const float*)d_in[2];
  const float* Wo = (const float*)d_in[3];
  const float* bo = (const float*)d_in[4];
  float* out = (float*)d_out;
  char* wbuf = (char*)d_ws;                  // 512 KiB weight image
  float* bias = (float*)(wbuf + WBYTES);     // 1 KiB bias

  prep_kernel<<<dim3(256), dim3(256), 0, stream>>>(Wd, bd, Wo, bo, wbuf, bias);
  cap_main<<<dim3(1024), dim3(THREADS), 0, stream>>>(x, wbuf, bias, out);
}